// Round 2
// baseline (350.596 us; speedup 1.0000x reference)
//
#include <hip/hip_runtime.h>
#include <hip/hip_fp16.h>
#include <math.h>

#define NN   128           // total nodes
#define BS   64            // samples per block == threads == one wave
#define SCAP 1056          // schedule slot capacity (worst case 1024 + overshoot)
#define RT_F 0x10000       // root flag in pcode

// fp16 LDS swizzle: element (node n, lane t) at n*64 + (t ^ ((n&15)<<1)).
// bank = ((t>>1) ^ (n&15)) & 31 -> compute phase (n fixed): 2-way, free;
// epilogue transpose (t fixed-ish, n varies): conflict-free.
#define IDX(n,t) ((n)*BS + ((t) ^ (((n)&15)<<1)))

// ws layout:
//   [0,     16896)  float4 wtab[SCAP]   {w0,w1,b,sigma} slot-ordered
//   [20480, 24704)  int    pcode[SCAP]  p0 | p1<<8 | root<<16 | node<<24
//   [24704, 25216)  int    slotmap[128] node -> canonical slot
//   [25216, 25220)  int    S (padded slot count, multiple of 32)
//   [28672, +128K)  float  pilot_out[128][256]

// ---------------------------------------------------------------- prep
// Greedy width-8 list scheduler: group g takes (up to) the first 8 nodes whose
// parents are in strictly earlier groups. Node ids are topological (parents <
// child), so >=1 node is scheduled per iteration -> terminates. Unfilled slots
// become replicas of node 0 (always a root; sigma-free, idempotent rewrite).
__global__ __launch_bounds__(128) void prep_kernel(
    const float* __restrict__ W, const float* __restrict__ b,
    const float* __restrict__ pm, const int* __restrict__ pidx,
    float4* __restrict__ wtab, int* __restrict__ pcode,
    int* __restrict__ slotmap, int* __restrict__ ngp)
{
    __shared__ int grp[NN], slot[NN], wcnt[2];
    __shared__ int nassigned, gdone, gfin;
    const int i = threadIdx.x, w = i >> 6, lane = i & 63;
    const float m0 = pm[2*i], m1 = pm[2*i+1];
    const int   p0 = pidx[2*i], p1 = pidx[2*i+1];
    const int   rt = (m0 == 0.0f && m1 == 0.0f) ? 1 : 0;
    grp[i] = -1; slot[i] = 0;
    if (i == 0) { nassigned = 0; gdone = 0; gfin = 0; }
    __syncthreads();
    for (int g = 0; g < NN; ++g) {
        int ready = (grp[i] < 0) && (rt || (grp[p0] >= 0 && grp[p1] >= 0));
        unsigned long long mask = __ballot(ready);
        if (lane == 0) wcnt[w] = __popcll(mask);
        __syncthreads();
        int base = w ? wcnt[0] : 0;
        int r = base + __popcll(mask & ((1ull << lane) - 1ull));
        if (ready && r < 8) { grp[i] = g; slot[i] = g*8 + r; }
        if (i == 0) {
            nassigned += min(wcnt[0] + wcnt[1], 8);
            if (nassigned >= NN) { gdone = 1; gfin = g; }
        }
        __syncthreads();
        if (gdone) break;
    }
    const int S0 = 8 * (gfin + 1);
    const int S  = (S0 + 31) & ~31;
    // default-fill every slot with a node-0 replica
    for (int k = i; k < SCAP; k += NN) {
        pcode[k] = RT_F;                       // p0=0,p1=0,root=1,node=0
        wtab[k]  = make_float4(0.f, 0.f, 0.f, 0.f);
    }
    __threadfence_block();
    __syncthreads();
    // canonical entries overwrite replicas
    pcode[slot[i]] = p0 | (p1 << 8) | (rt << 16) | (i << 24);
    wtab[slot[i]]  = make_float4(W[2*i]*m0, W[2*i+1]*m1, b[i], 0.f);
    slotmap[i] = slot[i];
    if (i == 0) ngp[0] = S;
}

// ---------------------------------------------------------------- pilot
// Noiseless calibration pass, 4 blocks x 64 samples. Literal-offset table
// loads; replica slots rewrite identical values (idempotent).
__global__ __launch_bounds__(64) void pilot_kernel(
    const float4* __restrict__ wtab, const int* __restrict__ pcode,
    const int* __restrict__ ngp, const float* __restrict__ root_pilot,
    float* __restrict__ pilot_out, int CAL)
{
    __shared__ _Float16 vals[NN * BS];
    const int tid = threadIdx.x;
    const int jj  = blockIdx.x * BS + tid;
    const int S   = ngp[0];
    for (int s0 = 0; s0 < S; s0 += 8) {
        int pc[8]; float4 wv[8];
        #pragma unroll
        for (int u = 0; u < 8; ++u) pc[u] = pcode[s0 + u];
        #pragma unroll
        for (int u = 0; u < 8; ++u) wv[u] = wtab[s0 + u];
        #pragma unroll
        for (int u = 0; u < 8; ++u) {
            int node = (pc[u] >> 24) & 0xff;
            float v;
            if (pc[u] & RT_F) {
                v = root_pilot[node * CAL + jj];
            } else {
                int q0 = pc[u] & 0xff, q1 = (pc[u] >> 8) & 0xff;
                float a = (float)vals[IDX(q0, tid)];
                float c = (float)vals[IDX(q1, tid)];
                v = fmaxf(fmaf(wv[u].x, a, fmaf(wv[u].y, c, wv[u].z)), 0.0f);
            }
            if (!isfinite(v)) v = 0.0f;
            vals[IDX(node, tid)] = (_Float16)v;
            pilot_out[node * CAL + jj] = v;
        }
    }
}

// ---------------------------------------------------------------- quant
// Bitonic sort of CAL=256 pilot values per node; sigma -> wtab[slot].w
__global__ __launch_bounds__(256) void quant_kernel(
    const float* __restrict__ pilot, const int* __restrict__ slotmap,
    float4* __restrict__ wtab, int CAL)
{
    __shared__ float s[256];
    const int tid = threadIdx.x;
    const int node = blockIdx.x;
    s[tid] = pilot[(size_t)node * CAL + tid];
    __syncthreads();
    for (int k = 2; k <= 256; k <<= 1) {
        for (int jj = k >> 1; jj > 0; jj >>= 1) {
            int ixj = tid ^ jj;
            if (ixj > tid) {
                float a = s[tid], bv = s[ixj];
                bool up = ((tid & k) == 0);
                if ((a > bv) == up) { s[tid] = bv; s[ixj] = a; }
            }
            __syncthreads();
        }
    }
    if (tid == 0) {
        float q25 = s[63]  + 0.75f * (s[64]  - s[63]);
        float q75 = s[191] + 0.25f * (s[192] - s[191]);
        ((float*)&wtab[slotmap[node]])[3] = 0.1f * fmaxf(q75 - q25, 1e-6f);
    }
}

// ---------------------------------------------------------------- main
__device__ __forceinline__ void mk_chunk(
    int c, int P, float (&zb)[2][16],
    const int* __restrict__ pcode, const float4* __restrict__ wtab,
    const float* __restrict__ root_main, const float* __restrict__ z,
    unsigned NS, size_t j, _Float16* vals, int tid)
{
    const int base = c * 16;
    // prefetch z for slots [base+16, base+32)
    #pragma unroll
    for (int u = 0; u < 16; ++u) {
        int pcN = pcode[base + 16 + u];
        const float* src = (pcN & RT_F) ? root_main : z;
        unsigned node = (unsigned)(pcN >> 24) & 0xffu;
        zb[P ^ 1][u] = src[(size_t)(node * NS) + j];
    }
    // compute slots [base, base+16)
    #pragma unroll
    for (int u = 0; u < 16; ++u) {
        int pc = pcode[base + u];
        float4 wv = wtab[base + u];
        float zv = zb[P][u];
        float v;
        if (pc & RT_F) {
            v = zv;
        } else {
            int q0 = pc & 0xff, q1 = (pc >> 8) & 0xff;
            float a  = (float)vals[IDX(q0, tid)];
            float c2 = (float)vals[IDX(q1, tid)];
            v = fmaxf(fmaf(wv.x, a, fmaf(wv.y, c2, wv.z)), 0.0f) + wv.w * zv;
        }
        if (!isfinite(v)) v = 0.0f;
        int node = (pc >> 24) & 0xff;
        vals[IDX(node, tid)] = (_Float16)v;
    }
}

__global__ __launch_bounds__(64) void main_kernel(
    const float4* __restrict__ wtab, const int* __restrict__ pcode,
    const int* __restrict__ ngp,
    const float* __restrict__ root_main, const float* __restrict__ z,
    const int* __restrict__ chosen, float* __restrict__ out, int NSi)
{
    __shared__ _Float16 vals[NN * BS];     // 16 KB -> 10 blocks/CU
    const int tid = threadIdx.x;
    const size_t j = (size_t)blockIdx.x * BS + tid;
    const unsigned NS = (unsigned)NSi;
    const int S = ngp[0];                   // multiple of 32
    const int nch = S >> 4;                 // even chunk count

    float zb[2][16];
    #pragma unroll
    for (int u = 0; u < 16; ++u) {
        int pc = pcode[u];
        const float* src = (pc & RT_F) ? root_main : z;
        unsigned node = (unsigned)(pc >> 24) & 0xffu;
        zb[0][u] = src[(size_t)(node * NS) + j];
    }

    for (int c = 0; c < nch; c += 2) {
        mk_chunk(c,     0, zb, pcode, wtab, root_main, z, NS, j, vals, tid);
        mk_chunk(c + 1, 1, zb, pcode, wtab, root_main, z, NS, j, vals, tid);
    }

    __syncthreads();   // epilogue reads other lanes' columns (cross-lane in wave)

    // transpose epilogue: out[sample][k], float4 coalesced stores
    float4* out4 = (float4*)(out + (size_t)blockIdx.x * BS * 64);
    #pragma unroll
    for (int it = 0; it < 16; ++it) {
        int cc = it * BS + tid;            // float4 chunk id, 0..1023
        int s  = cc >> 4;                  // local sample
        int k0 = (cc & 15) << 2;           // chosen base
        int n0 = chosen[k0], n1 = chosen[k0+1], n2 = chosen[k0+2], n3 = chosen[k0+3];
        float4 o;
        o.x = (float)vals[IDX(n0, s)];
        o.y = (float)vals[IDX(n1, s)];
        o.z = (float)vals[IDX(n2, s)];
        o.w = (float)vals[IDX(n3, s)];
        out4[cc] = o;
    }
}

extern "C" void kernel_launch(void* const* d_in, const int* in_sizes, int n_in,
                              void* d_out, int out_size, void* d_ws, size_t ws_size,
                              hipStream_t stream) {
    const float* W          = (const float*)d_in[1];
    const float* b          = (const float*)d_in[2];
    const float* root_pilot = (const float*)d_in[3];
    const float* root_main  = (const float*)d_in[4];
    const float* z          = (const float*)d_in[5];
    const float* pm         = (const float*)d_in[6];
    const int*   pidx       = (const int*)d_in[7];
    const int*   chosen     = (const int*)d_in[9];
    float* out = (float*)d_out;

    const int NS  = in_sizes[4] / NN;   // 262144
    const int CAL = in_sizes[3] / NN;   // 256

    char* ws = (char*)d_ws;
    float4* wtab    = (float4*)ws;
    int*    pcode   = (int*)(ws + 20480);
    int*    slotmap = (int*)(ws + 24704);
    int*    ngp     = (int*)(ws + 25216);
    float*  pilot   = (float*)(ws + 28672);

    prep_kernel <<<1, 128, 0, stream>>>(W, b, pm, pidx, wtab, pcode, slotmap, ngp);
    pilot_kernel<<<CAL / BS, BS, 0, stream>>>(wtab, pcode, ngp, root_pilot, pilot, CAL);
    quant_kernel<<<NN, 256, 0, stream>>>(pilot, slotmap, wtab, CAL);
    main_kernel <<<NS / BS, BS, 0, stream>>>(wtab, pcode, ngp, root_main, z, chosen, out, NS);
}

// Round 3
// 337.891 us; speedup vs baseline: 1.0376x; 1.0376x over previous
//
#include <hip/hip_runtime.h>
#include <hip/hip_fp16.h>
#include <math.h>

#define NN   128           // total nodes
#define BS   64            // samples per block == threads == one wave (main)
#define SCAP 1056          // schedule slot capacity (worst case 1024 + overshoot)
#define RT_F 0x10000       // root flag in pcode

// fp16 LDS swizzle: element (node n, lane t) at n*64 + (t ^ ((n&15)<<1)).
// bank = ((t>>1) ^ (n&15)) & 31 -> compute phase (n fixed): 2-way, free;
// epilogue transpose (t fixed-ish, n varies): conflict-free.
#define IDX(n,t) ((n)*BS + ((t) ^ (((n)&15)<<1)))

// ws layout:
//   [0,     16896)  float4 wtab[SCAP]   {w0,w1,b,sigma} slot-ordered
//   [20480, 24704)  int    pcode[SCAP]  p0 | p1<<8 | root<<16 | node<<24
//   [24704, 25216)  int    slotmap[128] node -> canonical slot
//   [25216, 25220)  int    S (padded slot count, multiple of 32)
//   [28672, +128K)  float  pilot_out[128][256]

// ---------------------------------------------------------------- prep+pilot
// Fused: block 0 builds the width-8 schedule (prep), then the same block runs
// the noiseless calibration pass with 256 threads = 256 samples (pilot).
// Pilot sample columns are thread-private -> no cross-thread deps in phase 2.
__global__ __launch_bounds__(256) void prep_pilot_kernel(
    const float* __restrict__ W, const float* __restrict__ b,
    const float* __restrict__ pm, const int* __restrict__ pidx,
    const float* __restrict__ root_pilot,
    float4* __restrict__ wtab, int* __restrict__ pcode,
    int* __restrict__ slotmap, int* __restrict__ ngp,
    float* __restrict__ pilot_out, int CAL)
{
    __shared__ _Float16 vals[NN * 256];    // 64 KB: pilot node values, [n*256 + j]
    __shared__ int grp[NN], slot[NN], wcnt[4];
    __shared__ int nassigned, gdone, gfin;
    const int i = threadIdx.x, w = i >> 6, lane = i & 63;

    // ---- phase 1: greedy width-8 list scheduler (threads 0..127 drive) ----
    int p0 = 0, p1 = 0, rt = 1;
    float m0 = 0.f, m1 = 0.f;
    if (i < NN) {
        m0 = pm[2*i]; m1 = pm[2*i+1];
        p0 = pidx[2*i]; p1 = pidx[2*i+1];
        rt = (m0 == 0.0f && m1 == 0.0f) ? 1 : 0;
        grp[i] = -1; slot[i] = 0;
    }
    if (i == 0) { nassigned = 0; gdone = 0; gfin = 0; }
    __syncthreads();
    for (int g = 0; g < NN; ++g) {
        int ready = (i < NN) && (grp[i] < 0) && (rt || (grp[p0] >= 0 && grp[p1] >= 0));
        unsigned long long mask = __ballot(ready);
        if (lane == 0) wcnt[w] = __popcll(mask);
        __syncthreads();
        int base = 0;
        #pragma unroll
        for (int ww = 0; ww < 4; ++ww) if (ww < w) base += wcnt[ww];
        int r = base + __popcll(mask & ((1ull << lane) - 1ull));
        if (ready && r < 8) { grp[i] = g; slot[i] = g*8 + r; }
        if (i == 0) {
            int tot = wcnt[0] + wcnt[1] + wcnt[2] + wcnt[3];
            nassigned += min(tot, 8);
            if (nassigned >= NN) { gdone = 1; gfin = g; }
        }
        __syncthreads();
        if (gdone) break;
    }
    const int S0 = 8 * (gfin + 1);
    const int S  = (S0 + 31) & ~31;
    // default-fill every slot with a node-0 replica (idempotent rewrite)
    for (int k = i; k < SCAP; k += 256) {
        pcode[k] = RT_F;                       // p0=0,p1=0,root=1,node=0
        wtab[k]  = make_float4(0.f, 0.f, 0.f, 0.f);
    }
    __threadfence_block();
    __syncthreads();
    // canonical entries overwrite replicas
    if (i < NN) {
        pcode[slot[i]] = p0 | (p1 << 8) | (rt << 16) | (i << 24);
        wtab[slot[i]]  = make_float4(W[2*i]*m0, W[2*i+1]*m1, b[i], 0.f);
        slotmap[i] = slot[i];
    }
    if (i == 0) ngp[0] = S;
    __threadfence_block();
    __syncthreads();

    // ---- phase 2: pilot pass, thread i owns sample column jj = i ----
    const int jj = i;                          // CAL == 256 by problem spec
    for (int s0 = 0; s0 < S; s0 += 8) {        // one schedule group per iter
        int pc[8]; float4 wv[8];
        #pragma unroll
        for (int u = 0; u < 8; ++u) pc[u] = pcode[s0 + u];
        #pragma unroll
        for (int u = 0; u < 8; ++u) wv[u] = wtab[s0 + u];
        // batched parent reads (parents are in strictly earlier groups)
        float pa[8], pb[8];
        #pragma unroll
        for (int u = 0; u < 8; ++u) {
            int q0 = pc[u] & 0xff, q1 = (pc[u] >> 8) & 0xff;
            pa[u] = (float)vals[q0 * 256 + jj];
            pb[u] = (float)vals[q1 * 256 + jj];
        }
        _Float16 res[8]; int nodes[8]; float vf[8];
        #pragma unroll
        for (int u = 0; u < 8; ++u) {
            nodes[u] = (pc[u] >> 24) & 0xff;
            float v;
            if (pc[u] & RT_F) {
                v = root_pilot[nodes[u] * CAL + jj];
            } else {
                v = fmaxf(fmaf(wv[u].x, pa[u], fmaf(wv[u].y, pb[u], wv[u].z)), 0.0f);
            }
            if (!isfinite(v)) v = 0.0f;
            vf[u] = v; res[u] = (_Float16)v;
        }
        #pragma unroll
        for (int u = 0; u < 8; ++u) {
            vals[nodes[u] * 256 + jj] = res[u];
            pilot_out[nodes[u] * CAL + jj] = vf[u];
        }
    }
}

// ---------------------------------------------------------------- quant
// Bitonic sort of CAL=256 pilot values per node; sigma -> wtab[slot].w
__global__ __launch_bounds__(256) void quant_kernel(
    const float* __restrict__ pilot, const int* __restrict__ slotmap,
    float4* __restrict__ wtab, int CAL)
{
    __shared__ float s[256];
    const int tid = threadIdx.x;
    const int node = blockIdx.x;
    s[tid] = pilot[(size_t)node * CAL + tid];
    __syncthreads();
    for (int k = 2; k <= 256; k <<= 1) {
        for (int jj = k >> 1; jj > 0; jj >>= 1) {
            int ixj = tid ^ jj;
            if (ixj > tid) {
                float a = s[tid], bv = s[ixj];
                bool up = ((tid & k) == 0);
                if ((a > bv) == up) { s[tid] = bv; s[ixj] = a; }
            }
            __syncthreads();
        }
    }
    if (tid == 0) {
        float q25 = s[63]  + 0.75f * (s[64]  - s[63]);
        float q75 = s[191] + 0.25f * (s[192] - s[191]);
        ((float*)&wtab[slotmap[node]])[3] = 0.1f * fmaxf(q75 - q25, 1e-6f);
    }
}

// ---------------------------------------------------------------- main
// Group-batched chunk: per 8-slot schedule group, issue all 16 parent ds_reads
// back-to-back, then 8 computes, then 8 ds_writes. Parents are guaranteed in
// strictly earlier groups, so reads-before-writes within a group is safe
// (replica rewrites of node 0 are value-idempotent). This takes the
// false-aliasing lgkmcnt drain once per group instead of once per slot.
__device__ __forceinline__ void mk_chunk(
    int c, int P, float (&zb)[2][16],
    const int* __restrict__ pcode, const float4* __restrict__ wtab,
    const float* __restrict__ root_main, const float* __restrict__ z,
    unsigned NS, size_t j, _Float16* vals, int tid)
{
    const int base = c * 16;
    // prefetch z for slots [base+16, base+32)
    #pragma unroll
    for (int u = 0; u < 16; ++u) {
        int pcN = pcode[base + 16 + u];
        const float* src = (pcN & RT_F) ? root_main : z;
        unsigned node = (unsigned)(pcN >> 24) & 0xffu;
        zb[P ^ 1][u] = src[(size_t)(node * NS) + j];
    }
    // two schedule groups of 8 slots each
    #pragma unroll
    for (int h = 0; h < 2; ++h) {
        int pc[8];
        #pragma unroll
        for (int u = 0; u < 8; ++u) pc[u] = pcode[base + h*8 + u];
        // batched parent reads
        float pa[8], pb[8];
        #pragma unroll
        for (int u = 0; u < 8; ++u) {
            int q0 = pc[u] & 0xff, q1 = (pc[u] >> 8) & 0xff;
            pa[u] = (float)vals[IDX(q0, tid)];
            pb[u] = (float)vals[IDX(q1, tid)];
        }
        // batched compute
        _Float16 res[8]; int nodes[8];
        #pragma unroll
        for (int u = 0; u < 8; ++u) {
            float4 wv = wtab[base + h*8 + u];
            float zv = zb[P][h*8 + u];
            float v;
            if (pc[u] & RT_F) {
                v = zv;
            } else {
                v = fmaxf(fmaf(wv.x, pa[u], fmaf(wv.y, pb[u], wv.z)), 0.0f) + wv.w * zv;
            }
            if (!isfinite(v)) v = 0.0f;
            nodes[u] = (pc[u] >> 24) & 0xff;
            res[u] = (_Float16)v;
        }
        // batched writes
        #pragma unroll
        for (int u = 0; u < 8; ++u) vals[IDX(nodes[u], tid)] = res[u];
    }
}

__global__ __launch_bounds__(64) void main_kernel(
    const float4* __restrict__ wtab, const int* __restrict__ pcode,
    const int* __restrict__ ngp,
    const float* __restrict__ root_main, const float* __restrict__ z,
    const int* __restrict__ chosen, float* __restrict__ out, int NSi)
{
    __shared__ _Float16 vals[NN * BS];     // 16 KB -> 10 blocks/CU
    const int tid = threadIdx.x;
    const size_t j = (size_t)blockIdx.x * BS + tid;
    const unsigned NS = (unsigned)NSi;
    const int S = ngp[0];                   // multiple of 32
    const int nch = S >> 4;                 // even chunk count

    float zb[2][16];
    #pragma unroll
    for (int u = 0; u < 16; ++u) {
        int pc = pcode[u];
        const float* src = (pc & RT_F) ? root_main : z;
        unsigned node = (unsigned)(pc >> 24) & 0xffu;
        zb[0][u] = src[(size_t)(node * NS) + j];
    }

    for (int c = 0; c < nch; c += 2) {
        mk_chunk(c,     0, zb, pcode, wtab, root_main, z, NS, j, vals, tid);
        mk_chunk(c + 1, 1, zb, pcode, wtab, root_main, z, NS, j, vals, tid);
    }

    __syncthreads();   // epilogue reads other lanes' columns (cross-lane in wave)

    // transpose epilogue: out[sample][k], float4 coalesced stores
    float4* out4 = (float4*)(out + (size_t)blockIdx.x * BS * 64);
    #pragma unroll
    for (int it = 0; it < 16; ++it) {
        int cc = it * BS + tid;            // float4 chunk id, 0..1023
        int s  = cc >> 4;                  // local sample
        int k0 = (cc & 15) << 2;           // chosen base
        int n0 = chosen[k0], n1 = chosen[k0+1], n2 = chosen[k0+2], n3 = chosen[k0+3];
        float4 o;
        o.x = (float)vals[IDX(n0, s)];
        o.y = (float)vals[IDX(n1, s)];
        o.z = (float)vals[IDX(n2, s)];
        o.w = (float)vals[IDX(n3, s)];
        out4[cc] = o;
    }
}

extern "C" void kernel_launch(void* const* d_in, const int* in_sizes, int n_in,
                              void* d_out, int out_size, void* d_ws, size_t ws_size,
                              hipStream_t stream) {
    const float* W          = (const float*)d_in[1];
    const float* b          = (const float*)d_in[2];
    const float* root_pilot = (const float*)d_in[3];
    const float* root_main  = (const float*)d_in[4];
    const float* z          = (const float*)d_in[5];
    const float* pm         = (const float*)d_in[6];
    const int*   pidx       = (const int*)d_in[7];
    const int*   chosen     = (const int*)d_in[9];
    float* out = (float*)d_out;

    const int NS  = in_sizes[4] / NN;   // 262144
    const int CAL = in_sizes[3] / NN;   // 256

    char* ws = (char*)d_ws;
    float4* wtab    = (float4*)ws;
    int*    pcode   = (int*)(ws + 20480);
    int*    slotmap = (int*)(ws + 24704);
    int*    ngp     = (int*)(ws + 25216);
    float*  pilot   = (float*)(ws + 28672);

    prep_pilot_kernel<<<1, 256, 0, stream>>>(W, b, pm, pidx, root_pilot,
                                             wtab, pcode, slotmap, ngp, pilot, CAL);
    quant_kernel<<<NN, 256, 0, stream>>>(pilot, slotmap, wtab, CAL);
    main_kernel <<<NS / BS, BS, 0, stream>>>(wtab, pcode, ngp, root_main, z, chosen, out, NS);
}